// Round 6
// baseline (427.753 us; speedup 1.0000x reference)
//
#include <hip/hip_runtime.h>
#include <hip/hip_bf16.h>
#include <cstddef>

namespace {

constexpr int N = 100000;
constexpr int IN = 256;
constexpr int H = 128;
constexpr int OUT = 16;
constexpr int R = 5;
constexpr int E = 100000;
constexpr int RE = R * E;
constexpr int NB = (N + 255) / 256;  // scan blocks

using short8 = __attribute__((ext_vector_type(8))) short;
using f32x4 = __attribute__((ext_vector_type(4))) float;

__device__ __forceinline__ float b2f(unsigned int u16) {
  union { unsigned int i; float f; } v;
  v.i = u16 << 16;
  return v.f;
}
__device__ __forceinline__ unsigned short f2b(float f) {
  union { float f; unsigned int u; } v;
  v.f = f;
  unsigned int r = v.u + 0x7fffu + ((v.u >> 16) & 1u);
  return (unsigned short)(r >> 16);
}

__global__ void deg_count(const int* __restrict__ dst, float* __restrict__ deg,
                          int* __restrict__ degtot) {
  int i = blockIdx.x * 256 + threadIdx.x;
  if (i < RE) {
    int d = dst[i];
    atomicAdd(&deg[(i / E) * N + d], 1.0f);
    atomicAdd(&degtot[d], 1);
  }
}

__global__ void inv_deg_k(float* __restrict__ deg) {
  int i = blockIdx.x * 256 + threadIdx.x;
  if (i < R * N) deg[i] = 1.0f / fmaxf(deg[i], 1.0f);
}

// ---- exclusive prefix scan over degtot ----
__global__ void scan_blk(const int* __restrict__ in, int* __restrict__ part,
                         int* __restrict__ bsum, int n) {
  __shared__ int tmp[256];
  int tid = threadIdx.x;
  int gid = blockIdx.x * 256 + tid;
  int v = (gid < n) ? in[gid] : 0;
  tmp[tid] = v;
  __syncthreads();
  for (int o = 1; o < 256; o <<= 1) {
    int t = (tid >= o) ? tmp[tid - o] : 0;
    __syncthreads();
    tmp[tid] += t;
    __syncthreads();
  }
  if (gid < n) part[gid] = tmp[tid] - v;
  if (tid == 255) bsum[blockIdx.x] = tmp[255];
}

__global__ void scan_top(const int* __restrict__ bsum, int* __restrict__ bscan, int nb) {
  __shared__ int tmp[512];
  int tid = threadIdx.x;
  int v = (tid < nb) ? bsum[tid] : 0;
  tmp[tid] = v;
  __syncthreads();
  for (int o = 1; o < 512; o <<= 1) {
    int t = (tid >= o) ? tmp[tid - o] : 0;
    __syncthreads();
    tmp[tid] += t;
    __syncthreads();
  }
  if (tid < nb) bscan[tid] = tmp[tid] - v;
}

__global__ void scan_add(int* __restrict__ part, const int* __restrict__ bscan, int n) {
  int gid = blockIdx.x * 256 + threadIdx.x;
  if (gid < n) part[gid] += bscan[gid >> 8];
}

__global__ void fill_csr(const int* __restrict__ src, const int* __restrict__ dst,
                         const float* __restrict__ coef1, const float* __restrict__ coef2,
                         const float* __restrict__ invdeg, const int* __restrict__ off,
                         int* __restrict__ cursor, int* __restrict__ esrc,
                         float2* __restrict__ ecA, float2* __restrict__ ecB) {
  int i = blockIdx.x * 256 + threadIdx.x;
  if (i >= RE) return;
  int r = i / E;
  int d = dst[i];
  int slot = off[d] + atomicAdd(&cursor[d], 1);
  float id = invdeg[r * N + d];
  esrc[slot] = src[i];
  ecA[slot] = make_float2(coef1[2 * r] * id, coef1[2 * r + 1] * id);
  ecB[slot] = make_float2(coef2[2 * r] * id, coef2[2 * r + 1] * id);
}

// pack W[K][NOUT] fp32 -> bf16 MFMA B-fragment order:
// wp[((kc*NCT+ct)*64 + lane)*8 + ii] = W[kc*32 + (lane>>4)*8 + ii][ct*16 + (lane&15)]
__global__ void pack_w(const float* __restrict__ W, unsigned short* __restrict__ wp,
                       int NOUT, int total) {
  int i = blockIdx.x * 256 + threadIdx.x;
  if (i >= total) return;
  int ii = i & 7;
  int lane = (i >> 3) & 63;
  int fb = i >> 9;
  int NCT = NOUT >> 4;
  int kc = fb / NCT, ct = fb - kc * NCT;
  int k = kc * 32 + ((lane >> 4) << 3) + ii;
  int col = (ct << 4) + (lane & 15);
  wp[i] = f2b(W[(size_t)k * NOUT + col]);
}

// pack basis2[2][128][16] as the [128][32] matrix (cols = [b0:16 | b1:16])
__global__ void pack_b2(const float* __restrict__ basis2, unsigned short* __restrict__ wp) {
  int i = blockIdx.x * 256 + threadIdx.x;
  if (i >= 128 * 32) return;
  int ii = i & 7;
  int lane = (i >> 3) & 63;
  int fb = i >> 9;            // NCT = 2
  int kc = fb >> 1, ct = fb & 1;
  int k = kc * 32 + ((lane >> 4) << 3) + ii;
  wp[i] = f2b(basis2[((size_t)ct * 128 + k) * 16 + (lane & 15)]);
}

// h = x @ w_embed + b_embed.  Barrier-free: 32 rows/wave, A-frags direct
// from global (fp32 -> bf16 in regs), B-frags from packed global (L2-hot).
__global__ __launch_bounds__(256) void gemm_embed(
    const float* __restrict__ x, const unsigned short* __restrict__ wpack,
    const float* __restrict__ bias, unsigned short* __restrict__ C) {
  const int tid = threadIdx.x;
  const int lane = tid & 63;
  const int wave = (blockIdx.x * 256 + tid) >> 6;
  const int base = wave * 32;
  if (base >= N) return;                 // N % 32 == 0: no partial waves
  const int r = lane & 15, g = lane >> 4;
  const short8* wfrag = (const short8*)wpack;

  f32x4 acc[2][8];
#pragma unroll
  for (int t = 0; t < 2; ++t)
#pragma unroll
    for (int ct = 0; ct < 8; ++ct) acc[t][ct] = (f32x4){0.f, 0.f, 0.f, 0.f};

  const float* a0 = x + (size_t)(base + r) * IN + g * 8;
  const float* a1 = a0 + (size_t)16 * IN;

#pragma unroll
  for (int kc = 0; kc < 8; ++kc) {
    float4 v0 = *(const float4*)(a0 + kc * 32);
    float4 v1 = *(const float4*)(a0 + kc * 32 + 4);
    float4 v2 = *(const float4*)(a1 + kc * 32);
    float4 v3 = *(const float4*)(a1 + kc * 32 + 4);
    short8 af0, af1;
    af0[0] = (short)f2b(v0.x); af0[1] = (short)f2b(v0.y);
    af0[2] = (short)f2b(v0.z); af0[3] = (short)f2b(v0.w);
    af0[4] = (short)f2b(v1.x); af0[5] = (short)f2b(v1.y);
    af0[6] = (short)f2b(v1.z); af0[7] = (short)f2b(v1.w);
    af1[0] = (short)f2b(v2.x); af1[1] = (short)f2b(v2.y);
    af1[2] = (short)f2b(v2.z); af1[3] = (short)f2b(v2.w);
    af1[4] = (short)f2b(v3.x); af1[5] = (short)f2b(v3.y);
    af1[6] = (short)f2b(v3.z); af1[7] = (short)f2b(v3.w);
#pragma unroll
    for (int ct = 0; ct < 8; ++ct) {
      short8 bf = wfrag[(kc * 8 + ct) * 64 + lane];
      acc[0][ct] = __builtin_amdgcn_mfma_f32_16x16x32_bf16(af0, bf, acc[0][ct], 0, 0, 0);
      acc[1][ct] = __builtin_amdgcn_mfma_f32_16x16x32_bf16(af1, bf, acc[1][ct], 0, 0, 0);
    }
  }

  // D: col = ct*16 + r, row = base + t*16 + g*4 + i
#pragma unroll
  for (int t = 0; t < 2; ++t)
#pragma unroll
    for (int ct = 0; ct < 8; ++ct) {
      int col = ct * 16 + r;
      float bs = bias[col];
#pragma unroll
      for (int i = 0; i < 4; ++i)
        C[(size_t)(base + t * 16 + g * 4 + i) * H + col] = f2b(acc[t][ct][i] + bs);
    }
}

// Fused: h2 = relu(u @ basis1 + bias1);  q = h2 @ wpB2.
// h2 never touches global — per-wave LDS transpose between the two MFMAs.
__global__ __launch_bounds__(256) void gemm_fused(
    const unsigned short* __restrict__ u, const unsigned short* __restrict__ wp1,
    const float* __restrict__ bias1, const unsigned short* __restrict__ wp2,
    unsigned short* __restrict__ q) {
  constexpr int LP2 = 132;               // pad: write/read bank spread
  __shared__ unsigned short hl[4][32][LP2];
  const int tid = threadIdx.x;
  const int lane = tid & 63;
  const int wv = tid >> 6;
  const int wave = (blockIdx.x * 256 + tid) >> 6;
  const int base = wave * 32;
  if (base >= N) return;                 // no block barrier anywhere: safe
  const int r = lane & 15, g = lane >> 4;
  const short8* wf1 = (const short8*)wp1;
  const short8* wf2 = (const short8*)wp2;

  f32x4 acc[2][8];
#pragma unroll
  for (int t = 0; t < 2; ++t)
#pragma unroll
    for (int ct = 0; ct < 8; ++ct) acc[t][ct] = (f32x4){0.f, 0.f, 0.f, 0.f};

  const unsigned short* a0 = u + (size_t)(base + r) * 256 + g * 8;
  const unsigned short* a1 = a0 + (size_t)16 * 256;

#pragma unroll
  for (int kc = 0; kc < 8; ++kc) {
    short8 af0 = *(const short8*)(a0 + kc * 32);
    short8 af1 = *(const short8*)(a1 + kc * 32);
#pragma unroll
    for (int ct = 0; ct < 8; ++ct) {
      short8 bf = wf1[(kc * 8 + ct) * 64 + lane];
      acc[0][ct] = __builtin_amdgcn_mfma_f32_16x16x32_bf16(af0, bf, acc[0][ct], 0, 0, 0);
      acc[1][ct] = __builtin_amdgcn_mfma_f32_16x16x32_bf16(af1, bf, acc[1][ct], 0, 0, 0);
    }
  }

  // epilogue 1: bias+relu -> per-wave LDS tile (rows 0..31 local)
#pragma unroll
  for (int t = 0; t < 2; ++t)
#pragma unroll
    for (int ct = 0; ct < 8; ++ct) {
      int col = ct * 16 + r;
      float bs = bias1[col];
#pragma unroll
      for (int i = 0; i < 4; ++i)
        hl[wv][t * 16 + g * 4 + i][col] = f2b(fmaxf(acc[t][ct][i] + bs, 0.f));
    }

  // wave-synchronous LDS fence (same-wave producer/consumer; rule #18)
  asm volatile("s_waitcnt lgkmcnt(0)" ::: "memory");
  __builtin_amdgcn_sched_barrier(0);

  // second GEMM: q_tile = h2_tile @ wp2   (K=128 -> KC=4, NCT=2)
  f32x4 acc2[2][2];
#pragma unroll
  for (int t = 0; t < 2; ++t)
#pragma unroll
    for (int ct = 0; ct < 2; ++ct) acc2[t][ct] = (f32x4){0.f, 0.f, 0.f, 0.f};

#pragma unroll
  for (int kc = 0; kc < 4; ++kc) {
    short8 af0 = *(const short8*)&hl[wv][r][kc * 32 + g * 8];
    short8 af1 = *(const short8*)&hl[wv][16 + r][kc * 32 + g * 8];
#pragma unroll
    for (int ct = 0; ct < 2; ++ct) {
      short8 bf = wf2[(kc * 2 + ct) * 64 + lane];
      acc2[0][ct] = __builtin_amdgcn_mfma_f32_16x16x32_bf16(af0, bf, acc2[0][ct], 0, 0, 0);
      acc2[1][ct] = __builtin_amdgcn_mfma_f32_16x16x32_bf16(af1, bf, acc2[1][ct], 0, 0, 0);
    }
  }

#pragma unroll
  for (int t = 0; t < 2; ++t)
#pragma unroll
    for (int ct = 0; ct < 2; ++ct) {
      int col = ct * 16 + r;
#pragma unroll
      for (int i = 0; i < 4; ++i)
        q[(size_t)(base + t * 16 + g * 4 + i) * 32 + col] = f2b(acc2[t][ct][i]);
    }
}

// layer-1 gather (CSR): one wave per dst node, h bf16 rows (256 B coalesced)
__global__ __launch_bounds__(256) void gather1(
    const int* __restrict__ off, const int* __restrict__ degtot,
    const int* __restrict__ esrc, const float2* __restrict__ ecA,
    const unsigned short* __restrict__ hbf, unsigned int* __restrict__ ubf) {
  int wid = blockIdx.x * 4 + (threadIdx.x >> 6);
  int lane = threadIdx.x & 63;
  if (wid >= N) return;
  int start = off[wid];
  int cnt = degtot[wid];
  float u0x = 0.f, u0y = 0.f, u1x = 0.f, u1y = 0.f;
  if (cnt > 0) {
    int s = esrc[start];
    float2 c = ecA[start];
    unsigned int hv = ((const unsigned int*)(hbf + (size_t)s * 128))[lane];
    for (int j = 1; j < cnt; ++j) {
      int sn = esrc[start + j];
      float2 cn = ecA[start + j];
      unsigned int hvn = ((const unsigned int*)(hbf + (size_t)sn * 128))[lane];
      float hx = b2f(hv & 0xffffu), hy = b2f(hv >> 16);
      u0x = fmaf(c.x, hx, u0x); u0y = fmaf(c.x, hy, u0y);
      u1x = fmaf(c.y, hx, u1x); u1y = fmaf(c.y, hy, u1y);
      s = sn; c = cn; hv = hvn;
    }
    float hx = b2f(hv & 0xffffu), hy = b2f(hv >> 16);
    u0x = fmaf(c.x, hx, u0x); u0y = fmaf(c.x, hy, u0y);
    u1x = fmaf(c.y, hx, u1x); u1y = fmaf(c.y, hy, u1y);
  }
  unsigned int* ur = ubf + (size_t)wid * 128;  // 256 bf16 = 128 dwords
  ur[lane]      = (unsigned int)f2b(u0x) | ((unsigned int)f2b(u0y) << 16);
  ur[64 + lane] = (unsigned int)f2b(u1x) | ((unsigned int)f2b(u1y) << 16);
}

// layer-2 gather: 16 lanes per node, q bf16, writes fp32 d_out (bias folded)
__global__ __launch_bounds__(256) void gather2(
    const int* __restrict__ off, const int* __restrict__ degtot,
    const int* __restrict__ esrc, const float2* __restrict__ ecB,
    const unsigned short* __restrict__ qbf, const float* __restrict__ bias2,
    float* __restrict__ out) {
  int node = blockIdx.x * 16 + (threadIdx.x >> 4);
  int k = threadIdx.x & 15;
  if (node >= N) return;
  int start = off[node];
  int cnt = degtot[node];
  float acc = bias2[k];
  for (int j = 0; j < cnt; ++j) {
    int s = esrc[start + j];
    float2 c = ecB[start + j];
    acc = fmaf(c.x, b2f(qbf[(size_t)s * 32 + k]), acc);
    acc = fmaf(c.y, b2f(qbf[(size_t)s * 32 + 16 + k]), acc);
  }
  out[(size_t)node * 16 + k] = acc;
}

}  // namespace

extern "C" void kernel_launch(void* const* d_in, const int* in_sizes, int n_in,
                              void* d_out, int out_size, void* d_ws, size_t ws_size,
                              hipStream_t stream) {
  const float* x       = (const float*)d_in[0];
  const int*   src     = (const int*)d_in[1];
  const int*   dst     = (const int*)d_in[2];
  const float* w_embed = (const float*)d_in[3];
  const float* b_embed = (const float*)d_in[4];
  const float* basis1  = (const float*)d_in[5];
  const float* coef1   = (const float*)d_in[6];
  const float* bias1   = (const float*)d_in[7];
  const float* basis2  = (const float*)d_in[8];
  const float* coef2   = (const float*)d_in[9];
  const float* bias2   = (const float*)d_in[10];
  float* out = (float*)d_out;

  // ws layout (16B-aligned sections)
  float2* ecA = (float2*)d_ws;                         // RE
  float2* ecB = ecA + RE;                              // RE
  float*  invdeg = (float*)(ecB + RE);                 // R*N
  int*    degtot = (int*)(invdeg + (size_t)R * N);     // N
  int*    off    = degtot + N;                         // N
  int*    bsum   = off + N;                            // 512
  int*    bscan  = bsum + 512;                         // 512
  int*    cursor = bscan + 512;                        // N
  int*    esrc   = cursor + N;                         // RE
  unsigned short* wp1  = (unsigned short*)(esrc + RE); // 256*128
  unsigned short* wpB1 = wp1 + 256 * 128;              // 256*128
  unsigned short* wpB2 = wpB1 + 256 * 128;             // 128*32
  unsigned short* h_bf = wpB2 + 128 * 32;              // N*128
  unsigned short* u_bf = h_bf + (size_t)N * 128;       // N*256
  unsigned short* q_bf = u_bf + (size_t)N * 256;       // N*32

  dim3 b256(256);
  hipMemsetAsync(invdeg, 0, (size_t)R * N * sizeof(float), stream);
  hipMemsetAsync(degtot, 0, (size_t)N * sizeof(int), stream);
  hipMemsetAsync(cursor, 0, (size_t)N * sizeof(int), stream);

  deg_count<<<(RE + 255) / 256, b256, 0, stream>>>(dst, invdeg, degtot);
  inv_deg_k<<<(R * N + 255) / 256, b256, 0, stream>>>(invdeg);
  scan_blk<<<NB, b256, 0, stream>>>(degtot, off, bsum, N);
  scan_top<<<1, dim3(512), 0, stream>>>(bsum, bscan, NB);
  scan_add<<<NB, b256, 0, stream>>>(off, bscan, N);
  fill_csr<<<(RE + 255) / 256, b256, 0, stream>>>(src, dst, coef1, coef2, invdeg,
                                                  off, cursor, esrc, ecA, ecB);
  pack_w<<<(256 * 128 + 255) / 256, b256, 0, stream>>>(w_embed, wp1, 128, 256 * 128);
  pack_w<<<(256 * 128 + 255) / 256, b256, 0, stream>>>(basis1, wpB1, 128, 256 * 128);
  pack_b2<<<(128 * 32 + 255) / 256, b256, 0, stream>>>(basis2, wpB2);

  int gwaves = (N + 31) / 32;                  // 3125
  int gblocks = (gwaves + 3) / 4;              // 782
  // h = x @ w_embed + b_embed   (barrier-free MFMA, direct-global A)
  gemm_embed<<<gblocks, b256, 0, stream>>>(x, wp1, b_embed, h_bf);
  // u[d] = [sum c0*h[s] | sum c1*h[s]]  (CSR gather, no atomics)
  gather1<<<(N + 3) / 4, b256, 0, stream>>>(off, degtot, esrc, ecA, h_bf,
                                            (unsigned int*)u_bf);
  // q = relu(u @ basis1 + bias1) @ wpB2   (fused, h2 stays on-chip)
  gemm_fused<<<gblocks, b256, 0, stream>>>(u_bf, wpB1, bias1, wpB2, q_bf);
  // out[d][k] = bias2[k] + sum (c0*q[s][k] + c1*q[s][16+k])
  gather2<<<(N + 15) / 16, b256, 0, stream>>>(off, degtot, esrc, ecB, q_bf, bias2, out);
}

// Round 7
// 379.510 us; speedup vs baseline: 1.1271x; 1.1271x over previous
//
#include <hip/hip_runtime.h>
#include <hip/hip_bf16.h>
#include <cstddef>
#include <cstdint>

namespace {

constexpr int N = 100000;
constexpr int IN = 256;
constexpr int H = 128;
constexpr int R = 5;
constexpr int E = 100000;
constexpr int RE = R * E;
constexpr int NB = (N + 255) / 256;  // scan blocks

using short8 = __attribute__((ext_vector_type(8))) short;
using f32x4 = __attribute__((ext_vector_type(4))) float;

__device__ __forceinline__ float b2f(unsigned int u16) {
  union { unsigned int i; float f; } v;
  v.i = u16 << 16;
  return v.f;
}
__device__ __forceinline__ unsigned short f2b(float f) {
  union { float f; unsigned int u; } v;
  v.f = f;
  unsigned int r = v.u + 0x7fffu + ((v.u >> 16) & 1u);
  return (unsigned short)(r >> 16);
}

// async global->LDS, 16B/lane (wave stages 1KB per call; LDS dest wave-uniform)
__device__ __forceinline__ void load_lds16(const void* g, void* l) {
  __builtin_amdgcn_global_load_lds(
      (const __attribute__((address_space(1))) void*)g,
      (__attribute__((address_space(3))) void*)l, 16, 0, 0);
}

__device__ __forceinline__ float sel5(int r, float a0, float a1, float a2,
                                      float a3, float a4) {
  return r == 0 ? a0 : (r == 1 ? a1 : (r == 2 ? a2 : (r == 3 ? a3 : a4)));
}

__global__ void deg_count(const int* __restrict__ dst, float* __restrict__ deg,
                          int* __restrict__ degtot) {
  int i = blockIdx.x * 256 + threadIdx.x;
  if (i < RE) {
    int d = dst[i];
    atomicAdd(&deg[(i / E) * N + d], 1.0f);
    atomicAdd(&degtot[d], 1);
  }
}

__global__ void inv_deg_k(float* __restrict__ deg) {
  int i = blockIdx.x * 256 + threadIdx.x;
  if (i < R * N) deg[i] = 1.0f / fmaxf(deg[i], 1.0f);
}

// ---- exclusive prefix scan over degtot ----
__global__ void scan_blk(const int* __restrict__ in, int* __restrict__ part,
                         int* __restrict__ bsum, int n) {
  __shared__ int tmp[256];
  int tid = threadIdx.x;
  int gid = blockIdx.x * 256 + tid;
  int v = (gid < n) ? in[gid] : 0;
  tmp[tid] = v;
  __syncthreads();
  for (int o = 1; o < 256; o <<= 1) {
    int t = (tid >= o) ? tmp[tid - o] : 0;
    __syncthreads();
    tmp[tid] += t;
    __syncthreads();
  }
  if (gid < n) part[gid] = tmp[tid] - v;
  if (tid == 255) bsum[blockIdx.x] = tmp[255];
}

__global__ void scan_top(const int* __restrict__ bsum, int* __restrict__ bscan, int nb) {
  __shared__ int tmp[512];
  int tid = threadIdx.x;
  int v = (tid < nb) ? bsum[tid] : 0;
  tmp[tid] = v;
  __syncthreads();
  for (int o = 1; o < 512; o <<= 1) {
    int t = (tid >= o) ? tmp[tid - o] : 0;
    __syncthreads();
    tmp[tid] += t;
    __syncthreads();
  }
  if (tid < nb) bscan[tid] = tmp[tid] - v;
}

__global__ void scan_add(int* __restrict__ part, const int* __restrict__ bscan, int n) {
  int gid = blockIdx.x * 256 + threadIdx.x;
  if (gid < n) part[gid] += bscan[gid >> 8];
}

// counting-sort edges; payload = src | (r<<20)  (4B/edge instead of 20B)
__global__ void fill_csr(const int* __restrict__ src, const int* __restrict__ dst,
                         const int* __restrict__ off, int* __restrict__ cursor,
                         int* __restrict__ epk) {
  int i = blockIdx.x * 256 + threadIdx.x;
  if (i >= RE) return;
  int r = i / E;
  int d = dst[i];
  int slot = off[d] + atomicAdd(&cursor[d], 1);
  epk[slot] = src[i] | (r << 20);
}

// all three weight packs in one kernel (bf16 MFMA B-fragment order)
__global__ void pack_all(const float* __restrict__ w_embed,
                         const float* __restrict__ basis1,
                         const float* __restrict__ basis2,
                         unsigned short* __restrict__ wp1,
                         unsigned short* __restrict__ wpB1,
                         unsigned short* __restrict__ wpB2) {
  int i = blockIdx.x * 256 + threadIdx.x;
  if (i < 32768) {
    int ii = i & 7, lane = (i >> 3) & 63, fb = i >> 9;
    int kc = fb >> 3, ct = fb & 7;
    int k = kc * 32 + ((lane >> 4) << 3) + ii, col = (ct << 4) + (lane & 15);
    wp1[i] = f2b(w_embed[(size_t)k * 128 + col]);
  } else if (i < 65536) {
    int j = i - 32768;
    int ii = j & 7, lane = (j >> 3) & 63, fb = j >> 9;
    int kc = fb >> 3, ct = fb & 7;
    int k = kc * 32 + ((lane >> 4) << 3) + ii, col = (ct << 4) + (lane & 15);
    wpB1[j] = f2b(basis1[(size_t)k * 128 + col]);
  } else if (i < 65536 + 4096) {
    int j = i - 65536;
    int ii = j & 7, lane = (j >> 3) & 63, fb = j >> 9;
    int kc = fb >> 1, ct = fb & 1;
    int k = kc * 32 + ((lane >> 4) << 3) + ii;
    wpB2[j] = f2b(basis2[((size_t)ct * 128 + k) * 16 + (lane & 15)]);
  }
}

// h = x @ w_embed + b_embed.  Wave-private LDS tile, async-staged, ZERO barriers.
// 16 rows/wave, full K=256 staged (16 x global_load_lds_dwordx4 = 16KB in flight).
__global__ __launch_bounds__(256) void gemm_embed(
    const float* __restrict__ x, const unsigned short* __restrict__ wpack,
    const float* __restrict__ bias, unsigned short* __restrict__ C) {
  __shared__ __align__(16) float alds[4][16][264];  // 264: +8 pad -> 2-way banks max
  const int tid = threadIdx.x, lane = tid & 63, wv = tid >> 6;
  const int base = blockIdx.x * 64 + wv * 16;
  if (base >= N) return;               // N%16==0: surviving waves fully valid
  const int r = lane & 15, g = lane >> 4;
  const short8* wfrag = (const short8*)wpack;

#pragma unroll
  for (int i = 0; i < 16; ++i)
    load_lds16(x + (size_t)(base + i) * IN + lane * 4, &alds[wv][i][0]);

  asm volatile("s_waitcnt vmcnt(0)" ::: "memory");
  __builtin_amdgcn_sched_barrier(0);

  f32x4 acc[8];
#pragma unroll
  for (int ct = 0; ct < 8; ++ct) acc[ct] = (f32x4){0.f, 0.f, 0.f, 0.f};

#pragma unroll
  for (int kc = 0; kc < 8; ++kc) {
    float4 v0 = *(const float4*)&alds[wv][r][kc * 32 + g * 8];
    float4 v1 = *(const float4*)&alds[wv][r][kc * 32 + g * 8 + 4];
    short8 af;
    af[0] = (short)f2b(v0.x); af[1] = (short)f2b(v0.y);
    af[2] = (short)f2b(v0.z); af[3] = (short)f2b(v0.w);
    af[4] = (short)f2b(v1.x); af[5] = (short)f2b(v1.y);
    af[6] = (short)f2b(v1.z); af[7] = (short)f2b(v1.w);
#pragma unroll
    for (int ct = 0; ct < 8; ++ct)
      acc[ct] = __builtin_amdgcn_mfma_f32_16x16x32_bf16(
          af, wfrag[(kc * 8 + ct) * 64 + lane], acc[ct], 0, 0, 0);
  }

#pragma unroll
  for (int ct = 0; ct < 8; ++ct) {
    int col = ct * 16 + r;
    float bs = bias[col];
#pragma unroll
    for (int i = 0; i < 4; ++i)
      C[(size_t)(base + g * 4 + i) * H + col] = f2b(acc[ct][i] + bs);
  }
}

// Fused: h2 = relu(u @ basis1 + bias1); q = h2 @ wp2.  Same wave-private
// async-staged structure; h2 round-trips through per-wave LDS only.
__global__ __launch_bounds__(256) void gemm_fused(
    const unsigned short* __restrict__ u, const unsigned short* __restrict__ wp1,
    const float* __restrict__ bias1, const unsigned short* __restrict__ wp2,
    unsigned short* __restrict__ q) {
  __shared__ __align__(16) unsigned short ust[4][8][520];  // row-pairs, +8sh pad
  __shared__ __align__(16) unsigned short hl[4][16][136];  // h2 tile, +8sh pad
  const int tid = threadIdx.x, lane = tid & 63, wv = tid >> 6;
  const int base = blockIdx.x * 64 + wv * 16;
  if (base >= N) return;
  const int r = lane & 15, g = lane >> 4;
  const short8* wf1 = (const short8*)wp1;
  const short8* wf2 = (const short8*)wp2;

#pragma unroll
  for (int p = 0; p < 8; ++p)   // one call stages rows 2p,2p+1 (1KB)
    load_lds16(u + (size_t)(base + 2 * p) * 256 + lane * 8, &ust[wv][p][0]);

  asm volatile("s_waitcnt vmcnt(0)" ::: "memory");
  __builtin_amdgcn_sched_barrier(0);

  f32x4 acc[8];
#pragma unroll
  for (int ct = 0; ct < 8; ++ct) acc[ct] = (f32x4){0.f, 0.f, 0.f, 0.f};

#pragma unroll
  for (int kc = 0; kc < 8; ++kc) {
    short8 af = *(const short8*)&ust[wv][r >> 1][(r & 1) * 256 + kc * 32 + g * 8];
#pragma unroll
    for (int ct = 0; ct < 8; ++ct)
      acc[ct] = __builtin_amdgcn_mfma_f32_16x16x32_bf16(
          af, wf1[(kc * 8 + ct) * 64 + lane], acc[ct], 0, 0, 0);
  }

  // bias + relu -> per-wave LDS h2 tile
#pragma unroll
  for (int ct = 0; ct < 8; ++ct) {
    int col = ct * 16 + r;
    float bs = bias1[col];
#pragma unroll
    for (int i = 0; i < 4; ++i)
      hl[wv][g * 4 + i][col] = f2b(fmaxf(acc[ct][i] + bs, 0.f));
  }

  asm volatile("s_waitcnt lgkmcnt(0)" ::: "memory");
  __builtin_amdgcn_sched_barrier(0);

  f32x4 acc2[2];
#pragma unroll
  for (int ct = 0; ct < 2; ++ct) acc2[ct] = (f32x4){0.f, 0.f, 0.f, 0.f};

#pragma unroll
  for (int kc = 0; kc < 4; ++kc) {
    short8 af = *(const short8*)&hl[wv][r][kc * 32 + g * 8];
#pragma unroll
    for (int ct = 0; ct < 2; ++ct)
      acc2[ct] = __builtin_amdgcn_mfma_f32_16x16x32_bf16(
          af, wf2[(kc * 2 + ct) * 64 + lane], acc2[ct], 0, 0, 0);
  }

#pragma unroll
  for (int ct = 0; ct < 2; ++ct) {
    int col = ct * 16 + r;
#pragma unroll
    for (int i = 0; i < 4; ++i)
      q[(size_t)(base + g * 4 + i) * 32 + col] = f2b(acc2[ct][i]);
  }
}

// layer-1 gather: one wave per dst node; per-node coef*invdeg in regs, 5-way select
__global__ __launch_bounds__(256) void gather1(
    const int* __restrict__ off, const int* __restrict__ degtot,
    const int* __restrict__ epk, const float* __restrict__ invdeg,
    const float* __restrict__ coef1, const unsigned short* __restrict__ hbf,
    unsigned int* __restrict__ ubf) {
  int wid = blockIdx.x * 4 + (threadIdx.x >> 6);
  int lane = threadIdx.x & 63;
  if (wid >= N) return;
  int start = off[wid];
  int cnt = degtot[wid];
  float i0 = invdeg[wid], i1 = invdeg[N + wid], i2 = invdeg[2 * N + wid];
  float i3 = invdeg[3 * N + wid], i4 = invdeg[4 * N + wid];
  float x0 = coef1[0] * i0, y0 = coef1[1] * i0;
  float x1 = coef1[2] * i1, y1 = coef1[3] * i1;
  float x2 = coef1[4] * i2, y2 = coef1[5] * i2;
  float x3 = coef1[6] * i3, y3 = coef1[7] * i3;
  float x4 = coef1[8] * i4, y4 = coef1[9] * i4;
  float u0x = 0.f, u0y = 0.f, u1x = 0.f, u1y = 0.f;
  if (cnt > 0) {
    int pk = epk[start];
    int s = pk & 0xFFFFF, rr = pk >> 20;
    unsigned int hv = ((const unsigned int*)(hbf + (size_t)s * 128))[lane];
    for (int j = 1; j < cnt; ++j) {
      int pkn = epk[start + j];
      int sn = pkn & 0xFFFFF, rn = pkn >> 20;
      unsigned int hvn = ((const unsigned int*)(hbf + (size_t)sn * 128))[lane];
      float c0 = sel5(rr, x0, x1, x2, x3, x4);
      float c1 = sel5(rr, y0, y1, y2, y3, y4);
      float hx = b2f(hv & 0xffffu), hy = b2f(hv >> 16);
      u0x = fmaf(c0, hx, u0x); u0y = fmaf(c0, hy, u0y);
      u1x = fmaf(c1, hx, u1x); u1y = fmaf(c1, hy, u1y);
      rr = rn; hv = hvn;
    }
    float c0 = sel5(rr, x0, x1, x2, x3, x4);
    float c1 = sel5(rr, y0, y1, y2, y3, y4);
    float hx = b2f(hv & 0xffffu), hy = b2f(hv >> 16);
    u0x = fmaf(c0, hx, u0x); u0y = fmaf(c0, hy, u0y);
    u1x = fmaf(c1, hx, u1x); u1y = fmaf(c1, hy, u1y);
  }
  unsigned int* ur = ubf + (size_t)wid * 128;
  ur[lane]      = (unsigned int)f2b(u0x) | ((unsigned int)f2b(u0y) << 16);
  ur[64 + lane] = (unsigned int)f2b(u1x) | ((unsigned int)f2b(u1y) << 16);
}

// layer-2 gather: 16 lanes per node, writes fp32 d_out (bias folded in)
__global__ __launch_bounds__(256) void gather2(
    const int* __restrict__ off, const int* __restrict__ degtot,
    const int* __restrict__ epk, const float* __restrict__ invdeg,
    const float* __restrict__ coef2, const unsigned short* __restrict__ qbf,
    const float* __restrict__ bias2, float* __restrict__ out) {
  int node = blockIdx.x * 16 + (threadIdx.x >> 4);
  int k = threadIdx.x & 15;
  if (node >= N) return;
  int start = off[node];
  int cnt = degtot[node];
  float i0 = invdeg[node], i1 = invdeg[N + node], i2 = invdeg[2 * N + node];
  float i3 = invdeg[3 * N + node], i4 = invdeg[4 * N + node];
  float x0 = coef2[0] * i0, y0 = coef2[1] * i0;
  float x1 = coef2[2] * i1, y1 = coef2[3] * i1;
  float x2 = coef2[4] * i2, y2 = coef2[5] * i2;
  float x3 = coef2[6] * i3, y3 = coef2[7] * i3;
  float x4 = coef2[8] * i4, y4 = coef2[9] * i4;
  float acc = bias2[k];
  for (int j = 0; j < cnt; ++j) {
    int pk = epk[start + j];
    int s = pk & 0xFFFFF, rr = pk >> 20;
    float c0 = sel5(rr, x0, x1, x2, x3, x4);
    float c1 = sel5(rr, y0, y1, y2, y3, y4);
    acc = fmaf(c0, b2f(qbf[(size_t)s * 32 + k]), acc);
    acc = fmaf(c1, b2f(qbf[(size_t)s * 32 + 16 + k]), acc);
  }
  out[(size_t)node * 16 + k] = acc;
}

}  // namespace

extern "C" void kernel_launch(void* const* d_in, const int* in_sizes, int n_in,
                              void* d_out, int out_size, void* d_ws, size_t ws_size,
                              hipStream_t stream) {
  const float* x       = (const float*)d_in[0];
  const int*   src     = (const int*)d_in[1];
  const int*   dst     = (const int*)d_in[2];
  const float* w_embed = (const float*)d_in[3];
  const float* b_embed = (const float*)d_in[4];
  const float* basis1  = (const float*)d_in[5];
  const float* coef1   = (const float*)d_in[6];
  const float* bias1   = (const float*)d_in[7];
  const float* basis2  = (const float*)d_in[8];
  const float* coef2   = (const float*)d_in[9];
  const float* bias2   = (const float*)d_in[10];
  float* out = (float*)d_out;

  // ws layout: [invdeg | degtot | cursor] contiguous -> single memset
  float* invdeg = (float*)d_ws;                        // R*N
  int*   degtot = (int*)(invdeg + (size_t)R * N);      // N
  int*   cursor = degtot + N;                          // N
  int*   off    = cursor + N;                          // N
  int*   bsum   = off + N;                             // 512
  int*   bscan  = bsum + 512;                          // 512
  int*   epk    = bscan + 512;                         // RE
  unsigned short* wp1  = (unsigned short*)(epk + RE);  // 256*128
  unsigned short* wpB1 = wp1 + 256 * 128;              // 256*128
  unsigned short* wpB2 = wpB1 + 256 * 128;             // 128*32
  unsigned short* h_bf = wpB2 + 128 * 32;              // N*128
  unsigned short* u_bf = h_bf + (size_t)N * 128;       // N*256
  unsigned short* q_bf = u_bf + (size_t)N * 256;       // N*32

  dim3 b256(256);
  hipMemsetAsync(invdeg, 0, (size_t)(R * N + 2 * N) * sizeof(float), stream);

  deg_count<<<(RE + 255) / 256, b256, 0, stream>>>(dst, invdeg, degtot);
  inv_deg_k<<<(R * N + 255) / 256, b256, 0, stream>>>(invdeg);
  scan_blk<<<NB, b256, 0, stream>>>(degtot, off, bsum, N);
  scan_top<<<1, dim3(512), 0, stream>>>(bsum, bscan, NB);
  scan_add<<<NB, b256, 0, stream>>>(off, bscan, N);
  fill_csr<<<(RE + 255) / 256, b256, 0, stream>>>(src, dst, off, cursor, epk);
  pack_all<<<(65536 + 4096 + 255) / 256, b256, 0, stream>>>(
      w_embed, basis1, basis2, wp1, wpB1, wpB2);

  int gblocks = (N / 16 + 3) / 4;  // 1563: 16 rows/wave, 4 waves/block
  // h = x @ w_embed + b_embed   (async-staged, barrier-free)
  gemm_embed<<<gblocks, b256, 0, stream>>>(x, wp1, b_embed, h_bf);
  // u[d] = [sum c0*h[s] | sum c1*h[s]]  (CSR gather)
  gather1<<<(N + 3) / 4, b256, 0, stream>>>(off, degtot, epk, invdeg, coef1,
                                            h_bf, (unsigned int*)u_bf);
  // q = relu(u @ basis1 + bias1) @ wpB2   (fused, h2 stays on-chip)
  gemm_fused<<<gblocks, b256, 0, stream>>>(u_bf, wpB1, bias1, wpB2, q_bf);
  // out[d][k] = bias2[k] + sum (c0*q[s][k] + c1*q[s][16+k])
  gather2<<<(N + 15) / 16, b256, 0, stream>>>(off, degtot, epk, invdeg, coef2,
                                              q_bf, bias2, out);
}